// Round 15
// baseline (105.679 us; speedup 1.0000x reference)
//
#include <hip/hip_runtime.h>
#include <hip/hip_bf16.h>

// MMD loss via single-plane fp16 MFMA Gram pass, fragment-major layout.
//   a16f[kb][row][8]: lane's fragment = 16B at ((kb*8192+row)*8), coalesced.
//   d2 = sq_i + sq_j - 2 dot (sq exact f32);  kernels = u+u^2+u^4+u^8+u^16.
// mmd_main = r13's measured-best structure (256 thr, 2x2 waves of 64x64,
//   triangle grid 2080, LDS-free free-running): 43.5us @ 33% occ. r12's
//   A-LDS (52.6) and r14's 512-thr dual-tile (59.5) both regressed -> kept.
// This round: kap unroll 4->8 (deeper load pipeline), setprio dropped
//   (m190: negative for MFMA-dense), r14's fused finalize + Horner epilogue.
// T1 XCD swizzle (2080 % 8 == 0 -> bijective).

#define N_TOTAL 8192
#define B_HALF 4096
#define D_DIM 256
#define TILE 128
#define NTILE 64          // 8192/128
#define NTRI 2080         // 64*65/2

typedef float f32x16 __attribute__((ext_vector_type(16)));
typedef _Float16 f16x8 __attribute__((ext_vector_type(8)));

__device__ __forceinline__ const float* row_base(const float* src, const float* tgt, int r) {
    return (r < B_HALF) ? src + (size_t)r * D_DIM : tgt + (size_t)(r - B_HALF) * D_DIM;
}

// 256 blocks x 32 rows: sq + colpart (coalesced row reads), then
// fragment-major fp16 convert with COALESCED 16B stores. Block 0 zeroes cnt.
__global__ __launch_bounds__(256) void prep_kernel(const float* __restrict__ src,
                                                   const float* __restrict__ tgt,
                                                   _Float16* __restrict__ a16f,
                                                   float* __restrict__ sq,
                                                   float* __restrict__ colpart,
                                                   unsigned* __restrict__ cnt) {
    int tid = threadIdx.x, w = tid >> 6, lane = tid & 63;
    int r0 = blockIdx.x * 32;
    if (blockIdx.x == 0 && tid == 0) *cnt = 0;   // visible after kernel end

    // row sq: each wave handles 8 rows, lane = float4 slot
    #pragma unroll
    for (int i = 0; i < 8; ++i) {
        int row = r0 + w * 8 + i;
        const float* rp = row_base(src, tgt, row);
        float4 v = ((const float4*)rp)[lane];
        float s = v.x*v.x + v.y*v.y + v.z*v.z + v.w*v.w;
        #pragma unroll
        for (int off = 32; off; off >>= 1) s += __shfl_down(s, off, 64);
        if (lane == 0) sq[row] = s;
    }

    // column partials: thread t sums column t over this block's 32 rows
    float c = 0.f;
    for (int r = r0; r < r0 + 32; ++r)
        c += row_base(src, tgt, r)[tid];
    colpart[blockIdx.x * D_DIM + tid] = c;

    // fragment-major convert: wave-task = (kb, 64-row group), 4 per wave.
    int wg = blockIdx.x * 4 + w;                   // 0..1023
    #pragma unroll
    for (int i = 0; i < 4; ++i) {
        int t  = wg * 4 + i;                       // 0..4095
        int kb = t >> 7, rg = t & 127;
        int row = rg * 64 + lane;
        const float* rp = row_base(src, tgt, row) + kb * 8;
        float4 v0 = ((const float4*)rp)[0];
        float4 v1 = ((const float4*)rp)[1];
        _Float16 h[8] = {(_Float16)v0.x, (_Float16)v0.y, (_Float16)v0.z, (_Float16)v0.w,
                         (_Float16)v1.x, (_Float16)v1.y, (_Float16)v1.z, (_Float16)v1.w};
        *(f16x8*)(a16f + ((size_t)kb * N_TOTAL + row) * 8) = *(f16x8*)h;
    }
}

__global__ __launch_bounds__(256) void bw_kernel(const float* __restrict__ sq,
                                                 const float* __restrict__ colpart,
                                                 float* __restrict__ negc,
                                                 double* __restrict__ accum) {
    __shared__ double red[256];
    int t = threadIdx.x;
    double s = 0.0;
    for (int i = t; i < N_TOTAL; i += 256) s += (double)sq[i];
    red[t] = s;
    __syncthreads();
    for (int off = 128; off; off >>= 1) {
        if (t < off) red[t] += red[t + off];
        __syncthreads();
    }
    double sumsq = red[0];
    __syncthreads();
    float c = 0.f;
    for (int k = 0; k < 256; ++k) c += colpart[k * D_DIM + t];
    red[t] = (double)c * (double)c;
    __syncthreads();
    for (int off = 128; off; off >>= 1) {
        if (t < off) red[t] += red[t + off];
        __syncthreads();
    }
    if (t == 0) {
        double S1 = 2.0 * (double)N_TOTAL * sumsq - 2.0 * red[0];
        double nn = (double)N_TOTAL * (double)N_TOTAL - (double)N_TOTAL;
        double bw = S1 / nn / 4.0;    // KERNEL_MUL^(KERNEL_NUM//2) = 4
        negc[0] = (float)(-1.4426950408889634 / (16.0 * bw));
        accum[0] = 0.0;
    }
}

__global__ __launch_bounds__(256, 4) void mmd_main(const _Float16* __restrict__ a16f,
                                                   const float* __restrict__ sq,
                                                   const float* __restrict__ negc,
                                                   double* __restrict__ accum,
                                                   unsigned* __restrict__ cnt,
                                                   float* __restrict__ out) {
    __shared__ float wsum[4];

    // T1: XCD swizzle (2080 % 8 == 0 -> bijective), then triangle decode (jt >= it)
    int b  = blockIdx.x;
    int bs = (b & 7) * (NTRI / 8) + (b >> 3);
    int it = 0, cum = 0;
    while (cum + (NTILE - it) <= bs) { cum += NTILE - it; ++it; }
    int jt = it + (bs - cum);

    int tid = threadIdx.x, lane = tid & 63, wid = tid >> 6;
    int wrow = wid >> 1, wcol = wid & 1;      // 2x2 wave grid; per-wave 64x64
    int rowA = it * TILE, rowB = jt * TILE;
    int c32 = lane & 31, khalf = lane >> 5;

    // fragment-major: lane fragment (kap, khalf): kb = kap*2+khalf,
    // 16B at ((kb*8192+row)*8). Consecutive lanes -> consecutive 16B.
    const _Float16* PA = a16f + (size_t)khalf * (N_TOTAL * 8)
                              + (size_t)(rowA + wrow * 64 + c32) * 8;
    const _Float16* PB = a16f + (size_t)khalf * (N_TOTAL * 8)
                              + (size_t)(rowB + wcol * 64 + c32) * 8;

    f32x16 acc[2][2] = {};

    #pragma unroll 8
    for (int kap = 0; kap < 16; ++kap) {      // K = 256 in steps of 16
        size_t ko = (size_t)kap * (N_TOTAL * 16);   // 2 k-blocks per step
        f16x8 af[2], bf[2];
        af[0] = *(const f16x8*)(PA + ko);
        af[1] = *(const f16x8*)(PA + ko + 32 * 8);
        bf[0] = *(const f16x8*)(PB + ko);
        bf[1] = *(const f16x8*)(PB + ko + 32 * 8);
        #pragma unroll
        for (int mt = 0; mt < 2; ++mt)
            #pragma unroll
            for (int nt = 0; nt < 2; ++nt)
                acc[mt][nt] = __builtin_amdgcn_mfma_f32_32x32x16_f16(af[mt], bf[nt], acc[mt][nt], 0, 0, 0);
    }

    // epilogue (VALU-trimmed): e = nc*si + nc*sj - 2nc*acc; u = exp2(min(e,0));
    // S = u + u^2(1 + u^2(1 + u^4(1 + u^8)))  [Horner].
    // C/D layout: col=lane&31, row=(reg&3)+8*(reg>>2)+4*khalf.
    float nc = *negc;
    float m2nc = -2.f * nc;
    float sj1[2];
    #pragma unroll
    for (int nt = 0; nt < 2; ++nt)
        sj1[nt] = nc * sq[rowB + wcol * 64 + nt * 32 + c32];
    float tu = 0.f, t2 = 0.f;
    #pragma unroll
    for (int mt = 0; mt < 2; ++mt) {
        #pragma unroll
        for (int reg = 0; reg < 16; ++reg) {
            int i = rowA + wrow * 64 + mt * 32 + (reg & 3) + 8 * (reg >> 2) + 4 * khalf;
            float si1 = nc * sq[i];
            #pragma unroll
            for (int nt = 0; nt < 2; ++nt) {
                float e  = fminf(fmaf(m2nc, acc[mt][nt][reg], si1 + sj1[nt]), 0.f);
                float u  = exp2f(e);
                float u2 = u * u, u4 = u2 * u2, u8 = u4 * u4;
                float in2 = fmaf(u4, 1.f + u8, 1.f);
                float in3 = fmaf(u2, in2, 1.f);
                tu += u;
                t2  = fmaf(u2, in3, t2);
            }
        }
    }
    float scale = (((it < 32) == (jt < 32)) ? 1.f : -1.f) * ((it == jt) ? 1.f : 2.f);
    float tsum = (tu + t2) * scale;

    #pragma unroll
    for (int off = 32; off; off >>= 1) tsum += __shfl_down(tsum, off, 64);
    if (lane == 0) wsum[wid] = tsum;
    __syncthreads();
    if (tid == 0) {
        float t = wsum[0] + wsum[1] + wsum[2] + wsum[3];
        atomicAdd(accum, (double)t);
        __threadfence();
        unsigned old = atomicAdd(cnt, 1u);
        if (old == NTRI - 1) {                // last block: fused finalize
            double v = atomicAdd(accum, 0.0); // coherent full-sum read
            out[0] = (float)(v / ((double)B_HALF * (double)B_HALF));
        }
    }
}

extern "C" void kernel_launch(void* const* d_in, const int* in_sizes, int n_in,
                              void* d_out, int out_size, void* d_ws, size_t ws_size,
                              hipStream_t stream) {
    const float* src = (const float*)d_in[0];
    const float* tgt = (const float*)d_in[1];
    float* out = (float*)d_out;

    char* ws = (char*)d_ws;
    float*    sq      = (float*)ws;                       // 32 KB
    float*    colpart = (float*)(ws + 32768);             // 256 x 256 f32 = 256 KB
    float*    negc    = (float*)(ws + 294912);
    double*   accum   = (double*)(ws + 294920);
    unsigned* cnt     = (unsigned*)(ws + 294928);
    _Float16* a16f    = (_Float16*)(ws + 327680);         // 4 MB plane (fragment-major)

    prep_kernel<<<256, 256, 0, stream>>>(src, tgt, a16f, sq, colpart, cnt);
    bw_kernel<<<1, 256, 0, stream>>>(sq, colpart, negc, accum);
    mmd_main<<<NTRI, 256, 0, stream>>>(a16f, sq, negc, accum, cnt, out);
}

// Round 16
// 103.516 us; speedup vs baseline: 1.0209x; 1.0209x over previous
//
#include <hip/hip_runtime.h>
#include <hip/hip_bf16.h>

// MMD loss via single-plane fp16 MFMA Gram pass, fragment-major layout.
//   a16f[kb][row][8]: lane's fragment = 16B at ((kb*8192+row)*8), coalesced.
//   d2 = sq_i + sq_j - 2 dot (sq exact f32);  kernels = u+u^2+u^4+u^8+u^16.
// mmd_main = r13's measured-best (43.5us): 256 thr, 2x2 waves of 64x64,
//   triangle grid 2080, LDS-free free-running, kap unroll 4, T5 setprio.
//   Variant ledger: A-LDS 52.6 (r12), 512-thr dual-tile 59.5 (r14),
//   unroll8/no-setprio 78.6 (r15) -> all regressed, restored r13 exact.
// T1 XCD swizzle (2080 % 8 == 0 -> bijective). Fused finalize (cnt).

#define N_TOTAL 8192
#define B_HALF 4096
#define D_DIM 256
#define TILE 128
#define NTILE 64          // 8192/128
#define NTRI 2080         // 64*65/2

typedef float f32x16 __attribute__((ext_vector_type(16)));
typedef _Float16 f16x8 __attribute__((ext_vector_type(8)));

__device__ __forceinline__ const float* row_base(const float* src, const float* tgt, int r) {
    return (r < B_HALF) ? src + (size_t)r * D_DIM : tgt + (size_t)(r - B_HALF) * D_DIM;
}

// 256 blocks x 32 rows: sq + colpart (coalesced row reads), then
// fragment-major fp16 convert with COALESCED 16B stores. Block 0 zeroes cnt.
__global__ __launch_bounds__(256) void prep_kernel(const float* __restrict__ src,
                                                   const float* __restrict__ tgt,
                                                   _Float16* __restrict__ a16f,
                                                   float* __restrict__ sq,
                                                   float* __restrict__ colpart,
                                                   unsigned* __restrict__ cnt) {
    int tid = threadIdx.x, w = tid >> 6, lane = tid & 63;
    int r0 = blockIdx.x * 32;
    if (blockIdx.x == 0 && tid == 0) *cnt = 0;   // visible after kernel end

    // row sq: each wave handles 8 rows, lane = float4 slot
    #pragma unroll
    for (int i = 0; i < 8; ++i) {
        int row = r0 + w * 8 + i;
        const float* rp = row_base(src, tgt, row);
        float4 v = ((const float4*)rp)[lane];
        float s = v.x*v.x + v.y*v.y + v.z*v.z + v.w*v.w;
        #pragma unroll
        for (int off = 32; off; off >>= 1) s += __shfl_down(s, off, 64);
        if (lane == 0) sq[row] = s;
    }

    // column partials: thread t sums column t over this block's 32 rows
    float c = 0.f;
    for (int r = r0; r < r0 + 32; ++r)
        c += row_base(src, tgt, r)[tid];
    colpart[blockIdx.x * D_DIM + tid] = c;

    // fragment-major convert: wave-task = (kb, 64-row group), 4 per wave.
    int wg = blockIdx.x * 4 + w;                   // 0..1023
    #pragma unroll
    for (int i = 0; i < 4; ++i) {
        int t  = wg * 4 + i;                       // 0..4095
        int kb = t >> 7, rg = t & 127;
        int row = rg * 64 + lane;
        const float* rp = row_base(src, tgt, row) + kb * 8;
        float4 v0 = ((const float4*)rp)[0];
        float4 v1 = ((const float4*)rp)[1];
        _Float16 h[8] = {(_Float16)v0.x, (_Float16)v0.y, (_Float16)v0.z, (_Float16)v0.w,
                         (_Float16)v1.x, (_Float16)v1.y, (_Float16)v1.z, (_Float16)v1.w};
        *(f16x8*)(a16f + ((size_t)kb * N_TOTAL + row) * 8) = *(f16x8*)h;
    }
}

__global__ __launch_bounds__(256) void bw_kernel(const float* __restrict__ sq,
                                                 const float* __restrict__ colpart,
                                                 float* __restrict__ negc,
                                                 double* __restrict__ accum) {
    __shared__ double red[256];
    int t = threadIdx.x;
    double s = 0.0;
    for (int i = t; i < N_TOTAL; i += 256) s += (double)sq[i];
    red[t] = s;
    __syncthreads();
    for (int off = 128; off; off >>= 1) {
        if (t < off) red[t] += red[t + off];
        __syncthreads();
    }
    double sumsq = red[0];
    __syncthreads();
    float c = 0.f;
    for (int k = 0; k < 256; ++k) c += colpart[k * D_DIM + t];
    red[t] = (double)c * (double)c;
    __syncthreads();
    for (int off = 128; off; off >>= 1) {
        if (t < off) red[t] += red[t + off];
        __syncthreads();
    }
    if (t == 0) {
        double S1 = 2.0 * (double)N_TOTAL * sumsq - 2.0 * red[0];
        double nn = (double)N_TOTAL * (double)N_TOTAL - (double)N_TOTAL;
        double bw = S1 / nn / 4.0;    // KERNEL_MUL^(KERNEL_NUM//2) = 4
        negc[0] = (float)(-1.4426950408889634 / (16.0 * bw));
        accum[0] = 0.0;
    }
}

__global__ __launch_bounds__(256, 4) void mmd_main(const _Float16* __restrict__ a16f,
                                                   const float* __restrict__ sq,
                                                   const float* __restrict__ negc,
                                                   double* __restrict__ accum,
                                                   unsigned* __restrict__ cnt,
                                                   float* __restrict__ out) {
    __shared__ float wsum[4];

    // T1: XCD swizzle (2080 % 8 == 0 -> bijective), then triangle decode (jt >= it)
    int b  = blockIdx.x;
    int bs = (b & 7) * (NTRI / 8) + (b >> 3);
    int it = 0, cum = 0;
    while (cum + (NTILE - it) <= bs) { cum += NTILE - it; ++it; }
    int jt = it + (bs - cum);

    int tid = threadIdx.x, lane = tid & 63, wid = tid >> 6;
    int wrow = wid >> 1, wcol = wid & 1;      // 2x2 wave grid; per-wave 64x64
    int rowA = it * TILE, rowB = jt * TILE;
    int c32 = lane & 31, khalf = lane >> 5;

    // fragment-major: lane fragment (kap, khalf): kb = kap*2+khalf,
    // 16B at ((kb*8192+row)*8). Consecutive lanes -> consecutive 16B.
    const _Float16* PA = a16f + (size_t)khalf * (N_TOTAL * 8)
                              + (size_t)(rowA + wrow * 64 + c32) * 8;
    const _Float16* PB = a16f + (size_t)khalf * (N_TOTAL * 8)
                              + (size_t)(rowB + wcol * 64 + c32) * 8;

    f32x16 acc[2][2] = {};

    #pragma unroll 4
    for (int kap = 0; kap < 16; ++kap) {      // K = 256 in steps of 16
        size_t ko = (size_t)kap * (N_TOTAL * 16);   // 2 k-blocks per step
        f16x8 af[2], bf[2];
        af[0] = *(const f16x8*)(PA + ko);
        af[1] = *(const f16x8*)(PA + ko + 32 * 8);
        bf[0] = *(const f16x8*)(PB + ko);
        bf[1] = *(const f16x8*)(PB + ko + 32 * 8);
        __builtin_amdgcn_s_setprio(1);        // T5: free-running waves regime
        #pragma unroll
        for (int mt = 0; mt < 2; ++mt)
            #pragma unroll
            for (int nt = 0; nt < 2; ++nt)
                acc[mt][nt] = __builtin_amdgcn_mfma_f32_32x32x16_f16(af[mt], bf[nt], acc[mt][nt], 0, 0, 0);
        __builtin_amdgcn_s_setprio(0);
    }

    // epilogue (VALU-trimmed): e = nc*si + nc*sj - 2nc*acc; u = exp2(min(e,0));
    // S = u + u^2(1 + u^2(1 + u^4(1 + u^8)))  [Horner].
    // C/D layout: col=lane&31, row=(reg&3)+8*(reg>>2)+4*khalf.
    float nc = *negc;
    float m2nc = -2.f * nc;
    float sj1[2];
    #pragma unroll
    for (int nt = 0; nt < 2; ++nt)
        sj1[nt] = nc * sq[rowB + wcol * 64 + nt * 32 + c32];
    float tu = 0.f, t2 = 0.f;
    #pragma unroll
    for (int mt = 0; mt < 2; ++mt) {
        #pragma unroll
        for (int reg = 0; reg < 16; ++reg) {
            int i = rowA + wrow * 64 + mt * 32 + (reg & 3) + 8 * (reg >> 2) + 4 * khalf;
            float si1 = nc * sq[i];
            #pragma unroll
            for (int nt = 0; nt < 2; ++nt) {
                float e  = fminf(fmaf(m2nc, acc[mt][nt][reg], si1 + sj1[nt]), 0.f);
                float u  = exp2f(e);
                float u2 = u * u, u4 = u2 * u2, u8 = u4 * u4;
                float in2 = fmaf(u4, 1.f + u8, 1.f);
                float in3 = fmaf(u2, in2, 1.f);
                tu += u;
                t2  = fmaf(u2, in3, t2);
            }
        }
    }
    float scale = (((it < 32) == (jt < 32)) ? 1.f : -1.f) * ((it == jt) ? 1.f : 2.f);
    float tsum = (tu + t2) * scale;

    #pragma unroll
    for (int off = 32; off; off >>= 1) tsum += __shfl_down(tsum, off, 64);
    if (lane == 0) wsum[wid] = tsum;
    __syncthreads();
    if (tid == 0) {
        float t = wsum[0] + wsum[1] + wsum[2] + wsum[3];
        atomicAdd(accum, (double)t);
        __threadfence();
        unsigned old = atomicAdd(cnt, 1u);
        if (old == NTRI - 1) {                // last block: fused finalize
            double v = atomicAdd(accum, 0.0); // coherent full-sum read
            out[0] = (float)(v / ((double)B_HALF * (double)B_HALF));
        }
    }
}

extern "C" void kernel_launch(void* const* d_in, const int* in_sizes, int n_in,
                              void* d_out, int out_size, void* d_ws, size_t ws_size,
                              hipStream_t stream) {
    const float* src = (const float*)d_in[0];
    const float* tgt = (const float*)d_in[1];
    float* out = (float*)d_out;

    char* ws = (char*)d_ws;
    float*    sq      = (float*)ws;                       // 32 KB
    float*    colpart = (float*)(ws + 32768);             // 256 x 256 f32 = 256 KB
    float*    negc    = (float*)(ws + 294912);
    double*   accum   = (double*)(ws + 294920);
    unsigned* cnt     = (unsigned*)(ws + 294928);
    _Float16* a16f    = (_Float16*)(ws + 327680);         // 4 MB plane (fragment-major)

    prep_kernel<<<256, 256, 0, stream>>>(src, tgt, a16f, sq, colpart, cnt);
    bw_kernel<<<1, 256, 0, stream>>>(sq, colpart, negc, accum);
    mmd_main<<<NTRI, 256, 0, stream>>>(a16f, sq, negc, accum, cnt, out);
}

// Round 17
// 72.070 us; speedup vs baseline: 1.4663x; 1.4363x over previous
//
#include <hip/hip_runtime.h>
#include <hip/hip_bf16.h>

// MMD loss via single-plane fp16 MFMA Gram pass, fragment-major layout.
//   a16f[kb][row][8]: lane's fragment = 16B at ((kb*8192+row)*8), coalesced.
//   d2 = sq_i + sq_j - 2 dot (sq exact f32);  kernels = u+u^2+u^4+u^8+u^16.
// EXACT restore of the measured-best round-12 submission (main 43.5us):
//   256 thr, 2x2 waves of 64x64, triangle grid 2080, LDS-free free-running,
//   kap unroll 4, T5 setprio, plain epilogue, SEPARATE finalize kernel.
// Regression ledger: fused finalize w/ __threadfence() = agent fence ->
//   buffer_wbl2/inv -> L2 invalidated 2080x -> main 76us (r14-16). The
//   fence, not unroll/setprio/geometry, was the regressor. NO threadfence.
// T1 XCD swizzle (2080 % 8 == 0 -> bijective).

#define N_TOTAL 8192
#define B_HALF 4096
#define D_DIM 256
#define TILE 128
#define NTILE 64          // 8192/128
#define NTRI 2080         // 64*65/2

typedef float f32x16 __attribute__((ext_vector_type(16)));
typedef _Float16 f16x8 __attribute__((ext_vector_type(8)));

__device__ __forceinline__ const float* row_base(const float* src, const float* tgt, int r) {
    return (r < B_HALF) ? src + (size_t)r * D_DIM : tgt + (size_t)(r - B_HALF) * D_DIM;
}

// 256 blocks x 32 rows: sq + colpart (coalesced row reads), then
// fragment-major fp16 convert with COALESCED 16B stores.
__global__ __launch_bounds__(256) void prep_kernel(const float* __restrict__ src,
                                                   const float* __restrict__ tgt,
                                                   _Float16* __restrict__ a16f,
                                                   float* __restrict__ sq,
                                                   float* __restrict__ colpart) {
    int tid = threadIdx.x, w = tid >> 6, lane = tid & 63;
    int r0 = blockIdx.x * 32;

    // row sq: each wave handles 8 rows, lane = float4 slot
    #pragma unroll
    for (int i = 0; i < 8; ++i) {
        int row = r0 + w * 8 + i;
        const float* rp = row_base(src, tgt, row);
        float4 v = ((const float4*)rp)[lane];
        float s = v.x*v.x + v.y*v.y + v.z*v.z + v.w*v.w;
        #pragma unroll
        for (int off = 32; off; off >>= 1) s += __shfl_down(s, off, 64);
        if (lane == 0) sq[row] = s;
    }

    // column partials: thread t sums column t over this block's 32 rows
    float c = 0.f;
    for (int r = r0; r < r0 + 32; ++r)
        c += row_base(src, tgt, r)[tid];
    colpart[blockIdx.x * D_DIM + tid] = c;

    // fragment-major convert: wave-task = (kb, 64-row group), 4 per wave.
    int wg = blockIdx.x * 4 + w;                   // 0..1023
    #pragma unroll
    for (int i = 0; i < 4; ++i) {
        int t  = wg * 4 + i;                       // 0..4095
        int kb = t >> 7, rg = t & 127;
        int row = rg * 64 + lane;
        const float* rp = row_base(src, tgt, row) + kb * 8;
        float4 v0 = ((const float4*)rp)[0];
        float4 v1 = ((const float4*)rp)[1];
        _Float16 h[8] = {(_Float16)v0.x, (_Float16)v0.y, (_Float16)v0.z, (_Float16)v0.w,
                         (_Float16)v1.x, (_Float16)v1.y, (_Float16)v1.z, (_Float16)v1.w};
        *(f16x8*)(a16f + ((size_t)kb * N_TOTAL + row) * 8) = *(f16x8*)h;
    }
}

__global__ __launch_bounds__(256) void bw_kernel(const float* __restrict__ sq,
                                                 const float* __restrict__ colpart,
                                                 float* __restrict__ negc,
                                                 double* __restrict__ accum) {
    __shared__ double red[256];
    int t = threadIdx.x;
    double s = 0.0;
    for (int i = t; i < N_TOTAL; i += 256) s += (double)sq[i];
    red[t] = s;
    __syncthreads();
    for (int off = 128; off; off >>= 1) {
        if (t < off) red[t] += red[t + off];
        __syncthreads();
    }
    double sumsq = red[0];
    __syncthreads();
    float c = 0.f;
    for (int k = 0; k < 256; ++k) c += colpart[k * D_DIM + t];
    red[t] = (double)c * (double)c;
    __syncthreads();
    for (int off = 128; off; off >>= 1) {
        if (t < off) red[t] += red[t + off];
        __syncthreads();
    }
    if (t == 0) {
        double S1 = 2.0 * (double)N_TOTAL * sumsq - 2.0 * red[0];
        double nn = (double)N_TOTAL * (double)N_TOTAL - (double)N_TOTAL;
        double bw = S1 / nn / 4.0;    // KERNEL_MUL^(KERNEL_NUM//2) = 4
        negc[0] = (float)(-1.4426950408889634 / (16.0 * bw));
        accum[0] = 0.0;
    }
}

__global__ __launch_bounds__(256, 4) void mmd_main(const _Float16* __restrict__ a16f,
                                                   const float* __restrict__ sq,
                                                   const float* __restrict__ negc,
                                                   double* __restrict__ accum) {
    __shared__ float wsum[4];

    // T1: XCD swizzle (2080 % 8 == 0 -> bijective), then triangle decode (jt >= it)
    int b  = blockIdx.x;
    int bs = (b & 7) * (NTRI / 8) + (b >> 3);
    int it = 0, cum = 0;
    while (cum + (NTILE - it) <= bs) { cum += NTILE - it; ++it; }
    int jt = it + (bs - cum);

    int tid = threadIdx.x, lane = tid & 63, wid = tid >> 6;
    int wrow = wid >> 1, wcol = wid & 1;      // 2x2 wave grid; per-wave 64x64
    int rowA = it * TILE, rowB = jt * TILE;
    int c32 = lane & 31, khalf = lane >> 5;

    // fragment-major: lane fragment (kap, khalf): kb = kap*2+khalf,
    // 16B at ((kb*8192+row)*8). Consecutive lanes -> consecutive 16B.
    const _Float16* PA = a16f + (size_t)khalf * (N_TOTAL * 8)
                              + (size_t)(rowA + wrow * 64 + c32) * 8;
    const _Float16* PB = a16f + (size_t)khalf * (N_TOTAL * 8)
                              + (size_t)(rowB + wcol * 64 + c32) * 8;

    f32x16 acc[2][2] = {};

    #pragma unroll 4
    for (int kap = 0; kap < 16; ++kap) {      // K = 256 in steps of 16
        size_t ko = (size_t)kap * (N_TOTAL * 16);   // 2 k-blocks per step
        f16x8 af[2], bf[2];
        af[0] = *(const f16x8*)(PA + ko);
        af[1] = *(const f16x8*)(PA + ko + 32 * 8);
        bf[0] = *(const f16x8*)(PB + ko);
        bf[1] = *(const f16x8*)(PB + ko + 32 * 8);
        __builtin_amdgcn_s_setprio(1);        // T5: free-running waves regime
        #pragma unroll
        for (int mt = 0; mt < 2; ++mt)
            #pragma unroll
            for (int nt = 0; nt < 2; ++nt)
                acc[mt][nt] = __builtin_amdgcn_mfma_f32_32x32x16_f16(af[mt], bf[nt], acc[mt][nt], 0, 0, 0);
        __builtin_amdgcn_s_setprio(0);
    }

    // fused epilogue: d2 -> 5-kernel sum. C/D: col=lane&31, row=(reg&3)+8*(reg>>2)+4*khalf
    float nc = *negc;
    float sjn[2];
    #pragma unroll
    for (int nt = 0; nt < 2; ++nt)
        sjn[nt] = sq[rowB + wcol * 64 + nt * 32 + c32];
    float tsum = 0.f;
    #pragma unroll
    for (int mt = 0; mt < 2; ++mt) {
        #pragma unroll
        for (int reg = 0; reg < 16; ++reg) {
            int i = rowA + wrow * 64 + mt * 32 + (reg & 3) + 8 * (reg >> 2) + 4 * khalf;
            float si = sq[i];
            #pragma unroll
            for (int nt = 0; nt < 2; ++nt) {
                float d2 = fmaxf(si + sjn[nt] - 2.0f * acc[mt][nt][reg], 0.f);
                float u  = exp2f(nc * d2);
                float u2 = u * u, u4 = u2 * u2, u8 = u4 * u4;
                tsum += u + u2 + u4 + u8 + u8 * u8;
            }
        }
    }
    float scale = (((it < 32) == (jt < 32)) ? 1.f : -1.f) * ((it == jt) ? 1.f : 2.f);
    tsum *= scale;

    #pragma unroll
    for (int off = 32; off; off >>= 1) tsum += __shfl_down(tsum, off, 64);
    if (lane == 0) wsum[wid] = tsum;
    __syncthreads();
    if (tid == 0) {
        float t = wsum[0] + wsum[1] + wsum[2] + wsum[3];
        atomicAdd(accum, (double)t);
    }
}

__global__ void finalize_kernel(const double* __restrict__ accum, float* __restrict__ out) {
    out[0] = (float)(accum[0] / ((double)B_HALF * (double)B_HALF));
}

extern "C" void kernel_launch(void* const* d_in, const int* in_sizes, int n_in,
                              void* d_out, int out_size, void* d_ws, size_t ws_size,
                              hipStream_t stream) {
    const float* src = (const float*)d_in[0];
    const float* tgt = (const float*)d_in[1];
    float* out = (float*)d_out;

    char* ws = (char*)d_ws;
    float*    sq      = (float*)ws;                       // 32 KB
    float*    colpart = (float*)(ws + 32768);             // 256 x 256 f32 = 256 KB
    float*    negc    = (float*)(ws + 294912);
    double*   accum   = (double*)(ws + 294920);
    _Float16* a16f    = (_Float16*)(ws + 327680);         // 4 MB plane (fragment-major)

    prep_kernel<<<256, 256, 0, stream>>>(src, tgt, a16f, sq, colpart);
    bw_kernel<<<1, 256, 0, stream>>>(sq, colpart, negc, accum);
    mmd_main<<<NTRI, 256, 0, stream>>>(a16f, sq, negc, accum);
    finalize_kernel<<<1, 1, 0, stream>>>(accum, out);
}

// Round 18
// 71.934 us; speedup vs baseline: 1.4691x; 1.0019x over previous
//
#include <hip/hip_runtime.h>
#include <hip/hip_bf16.h>

// MMD loss via single-plane fp16 MFMA Gram pass, fragment-major layout.
//   a16f[kb][row][8]: lane's fragment = 16B at ((kb*8192+row)*8), coalesced.
//   d2 = sq_i + sq_j - 2 dot (sq exact f32);  kernels = u+u^2+u^4+u^8+u^16.
// Baseline = r17 (main 43.7us): 256 thr, 2x2 waves of 64x64, triangle grid
//   2080, LDS-free free-running, kap unroll 4, T5 setprio, separate finalize.
// This round (two independent kernel-local changes, per-kernel attribution):
//   main: Horner/fmin epilogue (13 -> 11 VALU ops/pair) — first clean A/B
//         (r14-16 runs were confounded by the __threadfence L2-invalidate).
//   prep: colpart fused into the sq pass (kills one 8 MB read pass).
// NO __threadfence anywhere (fence = +16us/1000 blocks, r16 lesson).
// T1 XCD swizzle (2080 % 8 == 0 -> bijective).

#define N_TOTAL 8192
#define B_HALF 4096
#define D_DIM 256
#define TILE 128
#define NTILE 64          // 8192/128
#define NTRI 2080         // 64*65/2

typedef float f32x16 __attribute__((ext_vector_type(16)));
typedef _Float16 f16x8 __attribute__((ext_vector_type(8)));

__device__ __forceinline__ const float* row_base(const float* src, const float* tgt, int r) {
    return (r < B_HALF) ? src + (size_t)r * D_DIM : tgt + (size_t)(r - B_HALF) * D_DIM;
}

// 256 blocks x 32 rows. Pass A: sq + per-lane column accumulation (one 8MB
// read for both), LDS reduce across waves. Pass B: fragment-major fp16
// convert with COALESCED 16B stores (scattered loads, L2-absorbed).
__global__ __launch_bounds__(256) void prep_kernel(const float* __restrict__ src,
                                                   const float* __restrict__ tgt,
                                                   _Float16* __restrict__ a16f,
                                                   float* __restrict__ sq,
                                                   float* __restrict__ colpart) {
    __shared__ float cpl[4][D_DIM];   // per-wave column partials
    int tid = threadIdx.x, w = tid >> 6, lane = tid & 63;
    int r0 = blockIdx.x * 32;

    // sq + colpart in ONE pass: wave handles 8 rows; lane owns cols 4l..4l+3
    float c0 = 0.f, c1 = 0.f, c2 = 0.f, c3 = 0.f;
    #pragma unroll
    for (int i = 0; i < 8; ++i) {
        int row = r0 + w * 8 + i;
        const float* rp = row_base(src, tgt, row);
        float4 v = ((const float4*)rp)[lane];
        c0 += v.x; c1 += v.y; c2 += v.z; c3 += v.w;
        float s = v.x*v.x + v.y*v.y + v.z*v.z + v.w*v.w;
        #pragma unroll
        for (int off = 32; off; off >>= 1) s += __shfl_down(s, off, 64);
        if (lane == 0) sq[row] = s;
    }
    cpl[w][lane * 4 + 0] = c0;
    cpl[w][lane * 4 + 1] = c1;
    cpl[w][lane * 4 + 2] = c2;
    cpl[w][lane * 4 + 3] = c3;
    __syncthreads();
    colpart[blockIdx.x * D_DIM + tid] =
        cpl[0][tid] + cpl[1][tid] + cpl[2][tid] + cpl[3][tid];

    // fragment-major convert: wave-task = (kb, 64-row group), 4 per wave.
    int wg = blockIdx.x * 4 + w;                   // 0..1023
    #pragma unroll
    for (int i = 0; i < 4; ++i) {
        int t  = wg * 4 + i;                       // 0..4095
        int kb = t >> 7, rg = t & 127;
        int row = rg * 64 + lane;
        const float* rp = row_base(src, tgt, row) + kb * 8;
        float4 v0 = ((const float4*)rp)[0];
        float4 v1 = ((const float4*)rp)[1];
        _Float16 h[8] = {(_Float16)v0.x, (_Float16)v0.y, (_Float16)v0.z, (_Float16)v0.w,
                         (_Float16)v1.x, (_Float16)v1.y, (_Float16)v1.z, (_Float16)v1.w};
        *(f16x8*)(a16f + ((size_t)kb * N_TOTAL + row) * 8) = *(f16x8*)h;
    }
}

__global__ __launch_bounds__(256) void bw_kernel(const float* __restrict__ sq,
                                                 const float* __restrict__ colpart,
                                                 float* __restrict__ negc,
                                                 double* __restrict__ accum) {
    __shared__ double red[256];
    int t = threadIdx.x;
    double s = 0.0;
    for (int i = t; i < N_TOTAL; i += 256) s += (double)sq[i];
    red[t] = s;
    __syncthreads();
    for (int off = 128; off; off >>= 1) {
        if (t < off) red[t] += red[t + off];
        __syncthreads();
    }
    double sumsq = red[0];
    __syncthreads();
    float c = 0.f;
    for (int k = 0; k < 256; ++k) c += colpart[k * D_DIM + t];
    red[t] = (double)c * (double)c;
    __syncthreads();
    for (int off = 128; off; off >>= 1) {
        if (t < off) red[t] += red[t + off];
        __syncthreads();
    }
    if (t == 0) {
        double S1 = 2.0 * (double)N_TOTAL * sumsq - 2.0 * red[0];
        double nn = (double)N_TOTAL * (double)N_TOTAL - (double)N_TOTAL;
        double bw = S1 / nn / 4.0;    // KERNEL_MUL^(KERNEL_NUM//2) = 4
        negc[0] = (float)(-1.4426950408889634 / (16.0 * bw));
        accum[0] = 0.0;
    }
}

__global__ __launch_bounds__(256, 4) void mmd_main(const _Float16* __restrict__ a16f,
                                                   const float* __restrict__ sq,
                                                   const float* __restrict__ negc,
                                                   double* __restrict__ accum) {
    __shared__ float wsum[4];

    // T1: XCD swizzle (2080 % 8 == 0 -> bijective), then triangle decode (jt >= it)
    int b  = blockIdx.x;
    int bs = (b & 7) * (NTRI / 8) + (b >> 3);
    int it = 0, cum = 0;
    while (cum + (NTILE - it) <= bs) { cum += NTILE - it; ++it; }
    int jt = it + (bs - cum);

    int tid = threadIdx.x, lane = tid & 63, wid = tid >> 6;
    int wrow = wid >> 1, wcol = wid & 1;      // 2x2 wave grid; per-wave 64x64
    int rowA = it * TILE, rowB = jt * TILE;
    int c32 = lane & 31, khalf = lane >> 5;

    // fragment-major: lane fragment (kap, khalf): kb = kap*2+khalf,
    // 16B at ((kb*8192+row)*8). Consecutive lanes -> consecutive 16B.
    const _Float16* PA = a16f + (size_t)khalf * (N_TOTAL * 8)
                              + (size_t)(rowA + wrow * 64 + c32) * 8;
    const _Float16* PB = a16f + (size_t)khalf * (N_TOTAL * 8)
                              + (size_t)(rowB + wcol * 64 + c32) * 8;

    f32x16 acc[2][2] = {};

    #pragma unroll 4
    for (int kap = 0; kap < 16; ++kap) {      // K = 256 in steps of 16
        size_t ko = (size_t)kap * (N_TOTAL * 16);   // 2 k-blocks per step
        f16x8 af[2], bf[2];
        af[0] = *(const f16x8*)(PA + ko);
        af[1] = *(const f16x8*)(PA + ko + 32 * 8);
        bf[0] = *(const f16x8*)(PB + ko);
        bf[1] = *(const f16x8*)(PB + ko + 32 * 8);
        __builtin_amdgcn_s_setprio(1);        // T5: free-running waves regime
        #pragma unroll
        for (int mt = 0; mt < 2; ++mt)
            #pragma unroll
            for (int nt = 0; nt < 2; ++nt)
                acc[mt][nt] = __builtin_amdgcn_mfma_f32_32x32x16_f16(af[mt], bf[nt], acc[mt][nt], 0, 0, 0);
        __builtin_amdgcn_s_setprio(0);
    }

    // Horner epilogue: e = nc*si + nc*sj - 2nc*acc; u = exp2(min(e,0));
    // S = u + u^2(1 + u^2(1 + u^4(1 + u^8))). 11 VALU ops/pair vs 13.
    // C/D layout: col=lane&31, row=(reg&3)+8*(reg>>2)+4*khalf.
    float nc = *negc;
    float m2nc = -2.f * nc;
    float sj1[2];
    #pragma unroll
    for (int nt = 0; nt < 2; ++nt)
        sj1[nt] = nc * sq[rowB + wcol * 64 + nt * 32 + c32];
    float tu = 0.f, t2 = 0.f;
    #pragma unroll
    for (int mt = 0; mt < 2; ++mt) {
        #pragma unroll
        for (int reg = 0; reg < 16; ++reg) {
            int i = rowA + wrow * 64 + mt * 32 + (reg & 3) + 8 * (reg >> 2) + 4 * khalf;
            float si1 = nc * sq[i];
            #pragma unroll
            for (int nt = 0; nt < 2; ++nt) {
                float e  = fminf(fmaf(m2nc, acc[mt][nt][reg], si1 + sj1[nt]), 0.f);
                float u  = exp2f(e);
                float u2 = u * u, u4 = u2 * u2, u8 = u4 * u4;
                float in2 = fmaf(u4, 1.f + u8, 1.f);
                float in3 = fmaf(u2, in2, 1.f);
                tu += u;
                t2  = fmaf(u2, in3, t2);
            }
        }
    }
    float scale = (((it < 32) == (jt < 32)) ? 1.f : -1.f) * ((it == jt) ? 1.f : 2.f);
    float tsum = (tu + t2) * scale;

    #pragma unroll
    for (int off = 32; off; off >>= 1) tsum += __shfl_down(tsum, off, 64);
    if (lane == 0) wsum[wid] = tsum;
    __syncthreads();
    if (tid == 0) {
        float t = wsum[0] + wsum[1] + wsum[2] + wsum[3];
        atomicAdd(accum, (double)t);
    }
}

__global__ void finalize_kernel(const double* __restrict__ accum, float* __restrict__ out) {
    out[0] = (float)(accum[0] / ((double)B_HALF * (double)B_HALF));
}

extern "C" void kernel_launch(void* const* d_in, const int* in_sizes, int n_in,
                              void* d_out, int out_size, void* d_ws, size_t ws_size,
                              hipStream_t stream) {
    const float* src = (const float*)d_in[0];
    const float* tgt = (const float*)d_in[1];
    float* out = (float*)d_out;

    char* ws = (char*)d_ws;
    float*    sq      = (float*)ws;                       // 32 KB
    float*    colpart = (float*)(ws + 32768);             // 256 x 256 f32 = 256 KB
    float*    negc    = (float*)(ws + 294912);
    double*   accum   = (double*)(ws + 294920);
    _Float16* a16f    = (_Float16*)(ws + 327680);         // 4 MB plane (fragment-major)

    prep_kernel<<<256, 256, 0, stream>>>(src, tgt, a16f, sq, colpart);
    bw_kernel<<<1, 256, 0, stream>>>(sq, colpart, negc, accum);
    mmd_main<<<NTRI, 256, 0, stream>>>(a16f, sq, negc, accum);
    finalize_kernel<<<1, 1, 0, stream>>>(accum, out);
}